// Round 8
// baseline (312.826 us; speedup 1.0000x reference)
//
#include <hip/hip_runtime.h>
#include <math.h>

#define B_ 4
#define N_ 2048
#define DIM_ 1024
#define H_ 16
#define D_ 64
#define INNER_ 1024
#define BH_ (B_*H_)

#define A_ELEMS  (B_*N_*INNER_)        // 8388608
#define M_ELEMS  (BH_*D_*D_)           // 262144
#define Z_ELEMS  (BH_*D_)              // 4096

#define SC_LOG2E 0.18033688011112042f  // 0.125 * log2(e)

typedef __attribute__((ext_vector_type(8))) short short8;
typedef __attribute__((ext_vector_type(4))) float f32x4;
typedef __attribute__((ext_vector_type(4))) unsigned short us4;
typedef unsigned short u16;

// address-space pointer types for global_load_lds
typedef const unsigned int __attribute__((address_space(1))) gu32;
typedef unsigned int __attribute__((address_space(3))) su32;

__device__ __forceinline__ u16 f2bf(float f) {
    unsigned int u = __float_as_uint(f);
    u += 0x7fffu + ((u >> 16) & 1u);          // round-to-nearest-even
    return (u16)(u >> 16);
}
__device__ __forceinline__ float bf2f(u16 s) {
    return __uint_as_float(((unsigned int)s) << 16);
}
__device__ __forceinline__ float sigma_f(float x) {
    return x > 0.f ? x + 1.f : __expf(x);     // elu(x)+1
}
__device__ __forceinline__ short8 sig8(short8 in) {
    short8 out;
    u16* ip = (u16*)&in; u16* op = (u16*)&out;
    #pragma unroll
    for (int c = 0; c < 8; c++) op[c] = f2bf(sigma_f(bf2f(ip[c])));
    return out;
}

// ---------------------------------------------------------------------------
// Kernel 0a: x (fp32) -> xb (bf16)
// ---------------------------------------------------------------------------
__global__ __launch_bounds__(256) void cvt_x(const float* __restrict__ x,
                                             u16* __restrict__ xb) {
    long i = ((long)blockIdx.x * 256 + threadIdx.x) * 4;
    float4 f = *(const float4*)&x[i];
    us4 o = {f2bf(f.x), f2bf(f.y), f2bf(f.z), f2bf(f.w)};
    *(us4*)&xb[i] = o;
}

// ---------------------------------------------------------------------------
// Kernel 0b: W [1024][3072] fp32 -> Wt [3072][1024] bf16 (transpose via LDS)
// ---------------------------------------------------------------------------
__global__ __launch_bounds__(256) void cvt_w(const float* __restrict__ W,
                                             u16* __restrict__ Wt) {
    __shared__ u16 T[64 * 68];
    const int t  = threadIdx.x;
    const int n0 = blockIdx.x * 64, k0 = blockIdx.y * 64;
    #pragma unroll
    for (int i = 0; i < 4; i++) {
        int r  = (t >> 4) + i * 16;
        int c4 = (t & 15) * 4;
        float4 f = *(const float4*)&W[(long)(k0 + r) * 3072 + n0 + c4];
        T[(c4 + 0) * 68 + r] = f2bf(f.x);
        T[(c4 + 1) * 68 + r] = f2bf(f.y);
        T[(c4 + 2) * 68 + r] = f2bf(f.z);
        T[(c4 + 3) * 68 + r] = f2bf(f.w);
    }
    __syncthreads();
    #pragma unroll
    for (int i = 0; i < 4; i++) {
        int n  = (t >> 4) + i * 16;
        int k4 = (t & 15) * 4;
        us4 o;
        o.x = T[n * 68 + k4];     o.y = T[n * 68 + k4 + 1];
        o.z = T[n * 68 + k4 + 2]; o.w = T[n * 68 + k4 + 3];
        *(us4*)&Wt[(long)(n0 + n) * 1024 + k0 + k4] = o;
    }
}

// ---------------------------------------------------------------------------
// Kernel 1: qkv = x @ W_qkv via bf16 MFMA (unchanged from round 7).
// ---------------------------------------------------------------------------
__global__ __launch_bounds__(256) void qkv_mfma(
    const u16* __restrict__ xb, const u16* __restrict__ Wt,
    u16* __restrict__ q, u16* __restrict__ k, u16* __restrict__ v) {
    __shared__ u16 As[2][128 * 32];   // 8 KB each half
    __shared__ u16 Bs[2][128 * 32];
    const int t = threadIdx.x, w = t >> 6, lane = t & 63;
    const int quad = lane >> 4, l16 = lane & 15;

    // XCD swizzle: XCD k owns wg in [k*192, (k+1)*192) = 8 full m-rows
    const int lin = blockIdx.x;
    const int wg  = (lin & 7) * 192 + (lin >> 3);
    const int j0  = (wg % 24) * 128;
    const int m0  = (wg / 24) * 128;
    const int mw = (w >> 1) * 64, nw = (w & 1) * 64;

    const int srow = t >> 2;
    const int scol = (t & 3) * 8;

    const u16* pa0 = xb + (long)(m0 + srow) * 1024 + scol;
    const u16* pa1 = pa0 + (long)64 * 1024;
    const u16* pb0 = Wt + (long)(j0 + srow) * 1024 + scol;
    const u16* pb1 = pb0 + (long)64 * 1024;
    su32* da0 = (su32*)&As[0][srow * 32 + scol];
    su32* da1 = (su32*)&As[0][(srow + 64) * 32 + scol];
    su32* db0 = (su32*)&Bs[0][srow * 32 + scol];
    su32* db1 = (su32*)&Bs[0][(srow + 64) * 32 + scol];
    const int half = 128 * 32 / 2;    // As[1]-As[0] in u32 units

    f32x4 acc[4][4] = {};

    __builtin_amdgcn_global_load_lds((gu32*)pa0, da0, 16, 0, 0);
    __builtin_amdgcn_global_load_lds((gu32*)pa1, da1, 16, 0, 0);
    __builtin_amdgcn_global_load_lds((gu32*)pb0, db0, 16, 0, 0);
    __builtin_amdgcn_global_load_lds((gu32*)pb1, db1, 16, 0, 0);
    pa0 += 32; pa1 += 32; pb0 += 32; pb1 += 32;
    __syncthreads();   // drains vmcnt(0): tile 0 resident

    for (int kt = 0; kt < 32; ++kt) {
        const int cur = kt & 1;
        if (kt + 1 < 32) {
            const int nxs = (cur ^ 1) * half;
            __builtin_amdgcn_global_load_lds((gu32*)pa0, da0 + nxs, 16, 0, 0);
            __builtin_amdgcn_global_load_lds((gu32*)pa1, da1 + nxs, 16, 0, 0);
            __builtin_amdgcn_global_load_lds((gu32*)pb0, db0 + nxs, 16, 0, 0);
            __builtin_amdgcn_global_load_lds((gu32*)pb1, db1 + nxs, 16, 0, 0);
            pa0 += 32; pa1 += 32; pb0 += 32; pb1 += 32;
        }

        short8 af[4], bf[4];
        #pragma unroll
        for (int mt = 0; mt < 4; mt++)
            af[mt] = *(const short8*)&As[cur][(mw + mt * 16 + l16) * 32 + quad * 8];
        #pragma unroll
        for (int nt = 0; nt < 4; nt++)
            bf[nt] = *(const short8*)&Bs[cur][(nw + nt * 16 + l16) * 32 + quad * 8];
        #pragma unroll
        for (int mt = 0; mt < 4; mt++)
            #pragma unroll
            for (int nt = 0; nt < 4; nt++)
                acc[mt][nt] = __builtin_amdgcn_mfma_f32_16x16x32_bf16(
                    af[mt], bf[nt], acc[mt][nt], 0, 0, 0);

        __syncthreads();
    }

    // epilogue: scalar-hoisted addressing
    const int cb0 = j0 + nw;
    const int which = cb0 >> 10;
    u16* dstsel = (which == 0) ? q : (which == 1) ? k : v;
    const int bq = (m0 + mw) >> 11;
    const int nb = (m0 + mw) & 2047;
    const int lanoff = quad * 256 + l16;
    #pragma unroll
    for (int nt = 0; nt < 4; nt++) {
        const int cb = cb0 + nt * 16;
        const int hh = (cb & 1023) >> 6;
        const int dc = cb & 63;
        u16* dstp = dstsel + ((long)(bq * H_ + hh) * N_ + nb) * D_ + dc;
        #pragma unroll
        for (int mt = 0; mt < 4; mt++)
            #pragma unroll
            for (int r = 0; r < 4; r++)
                dstp[(mt * 16 + r) * 64 + lanoff] = f2bf(acc[mt][nt][r]);
    }
}

// ---------------------------------------------------------------------------
// Kernel 1b: vb [bh][n][d] -> vT [bh][d][n] (LDS transpose, XOR swizzle)
// ---------------------------------------------------------------------------
__global__ __launch_bounds__(256) void vt_transpose(
    const u16* __restrict__ vb, u16* __restrict__ vT) {
    __shared__ u16 T[64 * 72];
    const int bh = blockIdx.y;
    const int n0 = blockIdx.x * 64;
    const int t  = threadIdx.x;
    const int jj = t >> 3, kg = (t & 7) * 8;
    #pragma unroll
    for (int i = 0; i < 2; i++) {
        int j = jj + i * 32;
        short8 vv = *(const short8*)&vb[(((long)bh * N_ + n0 + j) << 6) + kg];
        u16* vp = (u16*)&vv;
        int jc = j ^ kg;
        #pragma unroll
        for (int c = 0; c < 8; c++) T[(kg + c) * 72 + jc] = vp[c];
    }
    __syncthreads();
    const int d = t >> 2, sg = (t & 3) * 16, xr = d & 56;
    short8 a0 = *(const short8*)&T[d * 72 + (sg ^ xr)];
    short8 a1 = *(const short8*)&T[d * 72 + ((sg + 8) ^ xr)];
    u16* dst = vT + ((long)bh * 64 + d) * 2048 + n0 + sg;
    *(short8*)dst       = a0;
    *(short8*)(dst + 8) = a1;
}

// ---------------------------------------------------------------------------
// Kernel 2: zero outA (fused kernel accumulates atomically), out_M = beta*M,
// out_Z = beta*Z. Grid 8192 x 256: thread i zeroes 4 floats of outA.
// ---------------------------------------------------------------------------
__global__ __launch_bounds__(256) void init_mz(
    const float* __restrict__ M, const float* __restrict__ Z,
    const float* __restrict__ beta_lin,
    float* __restrict__ outM, float* __restrict__ outZ,
    float* __restrict__ outA) {
    float beta = 1.f / (1.f + __expf(-beta_lin[0]));
    beta = fminf(fmaxf(beta, 0.9f), 0.999f);
    int i = blockIdx.x * 256 + threadIdx.x;
    float4 z4 = {0.f, 0.f, 0.f, 0.f};
    *(float4*)&outA[(long)i * 4] = z4;
    if (i < M_ELEMS) outM[i] = beta * M[i];
    if (i < Z_ELEMS) outZ[i] = beta * Z[i];
}

// ---------------------------------------------------------------------------
// Kernel 3+4 FUSED: block-specialized flash + linear attention.
// Grid 1024. sel = (lin>>3)&1: dispatch round-robins lin%8 across XCDs, so
// each XCD's arrival order alternates flash,linear,flash,... -> each CU
// co-hosts one flash block (MFMA/TRANS-heavy) and one linear block
// (VALU-expf-heavy): complementary pipes overlap instead of serializing.
// Both types on XCD x handle the same bh range (shared L2 for q/k/vt).
// outA ordering removed: init zeroes outA, BOTH epilogues atomicAdd
// (exactly 2 adds/element; float add is commutative -> bit-identical).
// LDS = flash 17.0K + linear 58.8K = 75.8 KB -> 2 blocks/CU (same
// 2 waves/SIMD both kernels already ran at).
// ---------------------------------------------------------------------------
__global__ __launch_bounds__(256) void fused_attn(
    const u16* __restrict__ qg, const u16* __restrict__ kg_,
    const u16* __restrict__ vTg, const float* __restrict__ Mg,
    const float* __restrict__ Zg, const float* __restrict__ beta_gate,
    float* __restrict__ outA, float* __restrict__ outM, float* __restrict__ outZ) {
    // flash LDS
    __shared__ u16 Ks[64 * 68];
    __shared__ u16 Vt[64 * 68];
    // linear LDS
    __shared__ u16 MTz[80 * 72];
    __shared__ u16 sqsh[64 * 72];
    __shared__ u16 sksh[64 * 72];
    __shared__ u16 skT[64 * 72];
    __shared__ u16 vTl[64 * 72];
    __shared__ u16 vmT[80 * 72];
    __shared__ float dks[64];

    const int lin  = blockIdx.x;
    const int xcd  = lin & 7;
    const int gidx = lin >> 3;           // 0..127
    const int sel  = gidx & 1;           // 0 = flash, 1 = linear
    const int u    = gidx >> 1;          // 0..63
    const int idx  = xcd * 64 + u;       // [0,512) per type, XCD-local bh

    const int t = threadIdx.x, w = t >> 6, lane = t & 63;
    const int quad = lane >> 4, l16 = lane & 15;

    if (sel == 0) {
        // =============== FLASH branch (round-6 kernel) ===============
        const int bh  = idx >> 3;
        const int n0  = (idx & 7) * 256;
        const int b = bh >> 4, h = bh & 15;
        const long bhN = (long)bh * N_;

        const int srow = t >> 2;
        const int sg   = (t & 3) * 16;
        const int jloc = srow & 31;
        const int krow = (srow & 32) + ((jloc & 4) << 2) + ((jloc >> 3) << 2) + (jloc & 3);

        const u16* kbase  = kg_ + (bhN << 6);
        const u16* vtbase = vTg + (long)bh * 64 * 2048;

        short8 qf[4][2];
        #pragma unroll
        for (int mi = 0; mi < 4; mi++) {
            long qrow = bhN + n0 + w * 64 + mi * 16 + l16;
            qf[mi][0] = *(const short8*)&qg[(qrow << 6) + quad * 8];
            qf[mi][1] = *(const short8*)&qg[(qrow << 6) + 32 + quad * 8];
            #pragma unroll
            for (int z = 0; z < 2; z++) {
                u16* p = (u16*)&qf[mi][z];
                #pragma unroll
                for (int c = 0; c < 8; c++) p[c] = f2bf(bf2f(p[c]) * SC_LOG2E);
            }
        }

        const short8 onesf = {0x3F80, 0x3F80, 0x3F80, 0x3F80,
                              0x3F80, 0x3F80, 0x3F80, 0x3F80};

        short8 kr0, kr1, vr0, vr1;
        {
            const u16* kp = kbase + ((long)srow << 6) + sg;
            kr0 = *(const short8*)kp;
            kr1 = *(const short8*)(kp + 8);
            const u16* vp = vtbase + (long)srow * 2048 + sg;
            vr0 = *(const short8*)vp;
            vr1 = *(const short8*)(vp + 8);
        }

        f32x4 of[4][4] = {};
        f32x4 ol[4] = {};

        for (int j0 = 0; j0 < N_; j0 += 64) {
            __syncthreads();
            *(short8*)&Ks[krow * 68 + sg]     = kr0;
            *(short8*)&Ks[krow * 68 + sg + 8] = kr1;
            *(short8*)&Vt[srow * 68 + sg]     = vr0;
            *(short8*)&Vt[srow * 68 + sg + 8] = vr1;
            __syncthreads();

            if (j0 + 64 < N_) {
                const u16* kp = kbase + ((long)(j0 + 64 + srow) << 6) + sg;
                kr0 = *(const short8*)kp;
                kr1 = *(const short8*)(kp + 8);
                const u16* vp = vtbase + (long)srow * 2048 + j0 + 64 + sg;
                vr0 = *(const short8*)vp;
                vr1 = *(const short8*)(vp + 8);
            }

            #pragma unroll
            for (int g2 = 0; g2 < 2; g2++) {
                const int rb = g2 * 32;
                short8 kA0 = *(const short8*)&Ks[(rb + l16) * 68 + quad * 8];
                short8 kA1 = *(const short8*)&Ks[(rb + l16) * 68 + 32 + quad * 8];
                short8 kB0 = *(const short8*)&Ks[(rb + 16 + l16) * 68 + quad * 8];
                short8 kB1 = *(const short8*)&Ks[(rb + 16 + l16) * 68 + 32 + quad * 8];
                short8 vf[4];
                #pragma unroll
                for (int nt = 0; nt < 4; nt++)
                    vf[nt] = *(const short8*)&Vt[(nt * 16 + l16) * 68 + rb + quad * 8];

                #pragma unroll
                for (int mi = 0; mi < 4; mi++) {
                    f32x4 st0 = {}, st1 = {};
                    __builtin_amdgcn_s_setprio(1);
                    st0 = __builtin_amdgcn_mfma_f32_16x16x32_bf16(kA0, qf[mi][0], st0, 0, 0, 0);
                    st0 = __builtin_amdgcn_mfma_f32_16x16x32_bf16(kA1, qf[mi][1], st0, 0, 0, 0);
                    st1 = __builtin_amdgcn_mfma_f32_16x16x32_bf16(kB0, qf[mi][0], st1, 0, 0, 0);
                    st1 = __builtin_amdgcn_mfma_f32_16x16x32_bf16(kB1, qf[mi][1], st1, 0, 0, 0);
                    __builtin_amdgcn_s_setprio(0);
                    float p0 = __builtin_amdgcn_exp2f(st0[0]);
                    float p1 = __builtin_amdgcn_exp2f(st0[1]);
                    float p2 = __builtin_amdgcn_exp2f(st0[2]);
                    float p3 = __builtin_amdgcn_exp2f(st0[3]);
                    float p4 = __builtin_amdgcn_exp2f(st1[0]);
                    float p5 = __builtin_amdgcn_exp2f(st1[1]);
                    float p6 = __builtin_amdgcn_exp2f(st1[2]);
                    float p7 = __builtin_amdgcn_exp2f(st1[3]);
                    short8 af;
                    unsigned int* au = (unsigned int*)&af;
                    au[0] = __builtin_amdgcn_perm(__float_as_uint(p1), __float_as_uint(p0),
                                                  0x07060302u);
                    au[1] = __builtin_amdgcn_perm(__float_as_uint(p3), __float_as_uint(p2),
                                                  0x07060302u);
                    au[2] = __builtin_amdgcn_perm(__float_as_uint(p5), __float_as_uint(p4),
                                                  0x07060302u);
                    au[3] = __builtin_amdgcn_perm(__float_as_uint(p7), __float_as_uint(p6),
                                                  0x07060302u);
                    __builtin_amdgcn_s_setprio(1);
                    ol[mi] = __builtin_amdgcn_mfma_f32_16x16x32_bf16(af, onesf, ol[mi], 0, 0, 0);
                    #pragma unroll
                    for (int nt = 0; nt < 4; nt++)
                        of[mi][nt] = __builtin_amdgcn_mfma_f32_16x16x32_bf16(
                            af, vf[nt], of[mi][nt], 0, 0, 0);
                    __builtin_amdgcn_s_setprio(0);
                }
            }
        }

        const float g  = 1.f / (1.f + __expf(-beta_gate[h]));
        const float gi = 1.f - g;
        #pragma unroll
        for (int mi = 0; mi < 4; mi++) {
            #pragma unroll
            for (int r = 0; r < 4; r++) {
                float sc = gi / ol[mi][r];
                int n = n0 + w * 64 + mi * 16 + quad * 4 + r;
                #pragma unroll
                for (int nt = 0; nt < 4; nt++) {
                    long idx2 = ((long)(b * N_ + n)) * INNER_ + h * 64 + nt * 16 + l16;
                    atomicAdd(&outA[idx2], sc * of[mi][nt][r]);
                }
            }
        }
    } else {
        // =============== LINEAR branch (round-7 kernel) ===============
        const int bh = idx >> 3;
        const int bx = idx & 7;
        const int b = bh >> 4, h = bh & 15;
        const long bhN = (long)bh * N_;

        #pragma unroll
        for (int i = 0; i < 4; i++) {
            int d  = (t >> 4) + i * 16;
            int c4 = (t & 15) * 4;
            float4 f = *(const float4*)&Mg[bh * 4096 + d * 64 + c4];
            MTz[(c4 + 0) * 72 + d] = f2bf(f.x);
            MTz[(c4 + 1) * 72 + d] = f2bf(f.y);
            MTz[(c4 + 2) * 72 + d] = f2bf(f.z);
            MTz[(c4 + 3) * 72 + d] = f2bf(f.w);
        }
        if (t < 64) {
            MTz[64 * 72 + t] = f2bf(Zg[bh * 64 + t]);
            vmT[64 * 72 + t] = f2bf(1.0f);
        }
        for (int e = t; e < 15 * 72; e += 256) {
            MTz[65 * 72 + e] = 0;
            vmT[65 * 72 + e] = 0;
        }
        if (t >= 64 && t < 72) { MTz[64 * 72 + t] = 0; vmT[64 * 72 + t] = 0; }

        const float g = 1.f / (1.f + __expf(-beta_gate[h]));

        f32x4 macc[5] = {};

        const int jj = t >> 3;
        const int kgp = (t & 7) * 8;
        const int srow = t >> 2;
        const int sg   = (t & 3) * 16;

        for (int c0 = 0; c0 < 256; c0 += 64) {
            const int n0c = bx * 256 + c0;
            __syncthreads();

            #pragma unroll
            for (int i = 0; i < 2; i++) {
                int j = jj + i * 32;
                long gb = ((bhN + n0c + j) << 6) + kgp;
                short8 q8 = sig8(*(const short8*)&qg[gb]);
                short8 k8 = sig8(*(const short8*)&kg_[gb]);
                *(short8*)&sqsh[j * 72 + kgp] = q8;
                *(short8*)&sksh[j * 72 + kgp] = k8;
                u16* kp = (u16*)&k8;
                int jc = j ^ kgp;
                #pragma unroll
                for (int c = 0; c < 8; c++) skT[(kgp + c) * 72 + jc] = kp[c];
            }
            {
                const u16* vp = vTg + ((long)bh * 64 + srow) * 2048 + n0c + sg;
                *(short8*)&vTl[srow * 72 + sg]     = *(const short8*)vp;
                *(short8*)&vTl[srow * 72 + sg + 8] = *(const short8*)(vp + 8);
            }
            __syncthreads();

            // --- MFMA1: A_raw = sq @ MTz ---
            {
                short8 a0 = *(const short8*)&sqsh[(w * 16 + l16) * 72 + quad * 8];
                short8 a1 = *(const short8*)&sqsh[(w * 16 + l16) * 72 + 32 + quad * 8];
                f32x4 am[5];
                #pragma unroll
                for (int ct = 0; ct < 5; ct++) {
                    short8 b0 = *(const short8*)&MTz[(ct * 16 + l16) * 72 + quad * 8];
                    short8 b1 = *(const short8*)&MTz[(ct * 16 + l16) * 72 + 32 + quad * 8];
                    f32x4 acc = {};
                    acc = __builtin_amdgcn_mfma_f32_16x16x32_bf16(a0, b0, acc, 0, 0, 0);
                    acc = __builtin_amdgcn_mfma_f32_16x16x32_bf16(a1, b1, acc, 0, 0, 0);
                    am[ct] = acc;
                }
                #pragma unroll
                for (int r = 0; r < 4; r++) {
                    float dq  = __shfl(am[4][r], lane & 48, 64);
                    float inv = __builtin_amdgcn_rcpf(dq);
                    int n = n0c + w * 16 + quad * 4 + r;
                    long row = ((long)(b * N_ + n)) * INNER_ + h * 64;
                    #pragma unroll
                    for (int ct = 0; ct < 4; ct++)
                        atomicAdd(&outA[row + ct * 16 + l16], g * am[ct][r] * inv);
                }
            }

            // --- MFMA2: momentT = MTz @ sk ---
            f32x4 mt_[4];
            {
                short8 a0 = *(const short8*)&MTz[(w * 16 + l16) * 72 + quad * 8];
                short8 a1 = *(const short8*)&MTz[(w * 16 + l16) * 72 + 32 + quad * 8];
                #pragma unroll
                for (int ct = 0; ct < 4; ct++) {
                    short8 b0 = *(const short8*)&sksh[(ct * 16 + l16) * 72 + quad * 8];
                    short8 b1 = *(const short8*)&sksh[(ct * 16 + l16) * 72 + 32 + quad * 8];
                    f32x4 acc = {};
                    acc = __builtin_amdgcn_mfma_f32_16x16x32_bf16(a0, b0, acc, 0, 0, 0);
                    acc = __builtin_amdgcn_mfma_f32_16x16x32_bf16(a1, b1, acc, 0, 0, 0);
                    mt_[ct] = acc;
                }
                short8 z0 = *(const short8*)&MTz[(64 + l16) * 72 + quad * 8];
                short8 z1 = *(const short8*)&MTz[(64 + l16) * 72 + 32 + quad * 8];
                short8 b0 = *(const short8*)&sksh[(w * 16 + l16) * 72 + quad * 8];
                short8 b1 = *(const short8*)&sksh[(w * 16 + l16) * 72 + 32 + quad * 8];
                f32x4 acc = {};
                acc = __builtin_amdgcn_mfma_f32_16x16x32_bf16(z0, b0, acc, 0, 0, 0);
                acc = __builtin_amdgcn_mfma_f32_16x16x32_bf16(z1, b1, acc, 0, 0, 0);
                if (quad == 0) dks[w * 16 + l16] = __builtin_amdgcn_rcpf(acc[0]);
            }
            __syncthreads();

            // --- vmT = vTl - momentT/dk (bf16) ---
            #pragma unroll
            for (int ct = 0; ct < 4; ct++) {
                float invdk = dks[ct * 16 + l16];
                #pragma unroll
                for (int r = 0; r < 4; r++) {
                    int vd = w * 16 + quad * 4 + r;
                    float vv = bf2f(vTl[vd * 72 + ct * 16 + l16]);
                    vmT[vd * 72 + ct * 16 + l16] = f2bf(vv - mt_[ct][r] * invdk);
                }
            }
            __syncthreads();

            // --- MFMA3: Macc += skT @ [vm | 1] ---
            {
                int drow = w * 16 + l16, xr = drow & 56;
                short8 a0 = *(const short8*)&skT[drow * 72 + ((quad * 8) ^ xr)];
                short8 a1 = *(const short8*)&skT[drow * 72 + ((32 + quad * 8) ^ xr)];
                #pragma unroll
                for (int ct = 0; ct < 5; ct++) {
                    short8 b0 = *(const short8*)&vmT[(ct * 16 + l16) * 72 + quad * 8];
                    short8 b1 = *(const short8*)&vmT[(ct * 16 + l16) * 72 + 32 + quad * 8];
                    macc[ct] = __builtin_amdgcn_mfma_f32_16x16x32_bf16(a0, b0, macc[ct], 0, 0, 0);
                    macc[ct] = __builtin_amdgcn_mfma_f32_16x16x32_bf16(a1, b1, macc[ct], 0, 0, 0);
                }
            }
        }

        #pragma unroll
        for (int ct = 0; ct < 4; ct++)
            #pragma unroll
            for (int r = 0; r < 4; r++) {
                int d = w * 16 + quad * 4 + r;
                atomicAdd(&outM[bh * 4096 + d * 64 + ct * 16 + l16], macc[ct][r]);
            }
        if (l16 == 0)
            #pragma unroll
            for (int r = 0; r < 4; r++)
                atomicAdd(&outZ[bh * 64 + w * 16 + quad * 4 + r], macc[4][r]);
    }
}

extern "C" void kernel_launch(void* const* d_in, const int* in_sizes, int n_in,
                              void* d_out, int out_size, void* d_ws, size_t ws_size,
                              hipStream_t stream) {
    const float* x         = (const float*)d_in[0];
    const float* M         = (const float*)d_in[1];
    const float* Z         = (const float*)d_in[2];
    const float* W         = (const float*)d_in[3];
    const float* beta_lin  = (const float*)d_in[4];
    const float* beta_gate = (const float*)d_in[5];

    float* out  = (float*)d_out;
    float* outA = out;
    float* outM = out + A_ELEMS;
    float* outZ = out + A_ELEMS + M_ELEMS;

    u16* xb = (u16*)d_ws;                         // [8192][1024]
    u16* Wt = xb + (size_t)8192 * 1024;           // [3072][1024]
    u16* qb = Wt + (size_t)3072 * 1024;           // [bh][n][d]
    u16* kb = qb + (size_t)BH_ * N_ * D_;         // [bh][n][d]
    u16* vb = kb + (size_t)BH_ * N_ * D_;         // [bh][n][d]
    u16* vt = vb + (size_t)BH_ * N_ * D_;         // [bh][d][n]

    cvt_x<<<dim3(A_ELEMS / 1024), 256, 0, stream>>>(x, xb);
    cvt_w<<<dim3(48, 16), 256, 0, stream>>>(W, Wt);
    qkv_mfma<<<dim3(1536), 256, 0, stream>>>(xb, Wt, qb, kb, vb);
    vt_transpose<<<dim3(N_ / 64, BH_), 256, 0, stream>>>(vb, vt);
    init_mz<<<dim3(A_ELEMS / 1024), 256, 0, stream>>>(M, Z, beta_lin, outM, outZ, outA);
    fused_attn<<<dim3(1024), 256, 0, stream>>>(qb, kb, vt, M, Z, beta_gate,
                                               outA, outM, outZ);
}

// Round 9
// 262.929 us; speedup vs baseline: 1.1898x; 1.1898x over previous
//
#include <hip/hip_runtime.h>
#include <math.h>

#define B_ 4
#define N_ 2048
#define DIM_ 1024
#define H_ 16
#define D_ 64
#define INNER_ 1024
#define BH_ (B_*H_)

#define A_ELEMS  (B_*N_*INNER_)        // 8388608
#define M_ELEMS  (BH_*D_*D_)           // 262144
#define Z_ELEMS  (BH_*D_)              // 4096

#define SC_LOG2E 0.18033688011112042f  // 0.125 * log2(e)

typedef __attribute__((ext_vector_type(8))) short short8;
typedef __attribute__((ext_vector_type(4))) float f32x4;
typedef __attribute__((ext_vector_type(4))) unsigned short us4;
typedef unsigned short u16;

// address-space pointer types for global_load_lds
typedef const unsigned int __attribute__((address_space(1))) gu32;
typedef unsigned int __attribute__((address_space(3))) su32;

__device__ __forceinline__ u16 f2bf(float f) {
    unsigned int u = __float_as_uint(f);
    u += 0x7fffu + ((u >> 16) & 1u);          // round-to-nearest-even
    return (u16)(u >> 16);
}
__device__ __forceinline__ float bf2f(u16 s) {
    return __uint_as_float(((unsigned int)s) << 16);
}
__device__ __forceinline__ float sigma_f(float x) {
    return x > 0.f ? x + 1.f : __expf(x);     // elu(x)+1
}
__device__ __forceinline__ short8 sig8(short8 in) {
    short8 out;
    u16* ip = (u16*)&in; u16* op = (u16*)&out;
    #pragma unroll
    for (int c = 0; c < 8; c++) op[c] = f2bf(sigma_f(bf2f(ip[c])));
    return out;
}

// ---------------------------------------------------------------------------
// Kernel 0a: x (fp32) -> xb (bf16)
// ---------------------------------------------------------------------------
__global__ __launch_bounds__(256) void cvt_x(const float* __restrict__ x,
                                             u16* __restrict__ xb) {
    long i = ((long)blockIdx.x * 256 + threadIdx.x) * 4;
    float4 f = *(const float4*)&x[i];
    us4 o = {f2bf(f.x), f2bf(f.y), f2bf(f.z), f2bf(f.w)};
    *(us4*)&xb[i] = o;
}

// ---------------------------------------------------------------------------
// Kernel 0b: W [1024][3072] fp32 -> Wt [3072][1024] bf16 (transpose via LDS)
// ---------------------------------------------------------------------------
__global__ __launch_bounds__(256) void cvt_w(const float* __restrict__ W,
                                             u16* __restrict__ Wt) {
    __shared__ u16 T[64 * 68];
    const int t  = threadIdx.x;
    const int n0 = blockIdx.x * 64, k0 = blockIdx.y * 64;
    #pragma unroll
    for (int i = 0; i < 4; i++) {
        int r  = (t >> 4) + i * 16;
        int c4 = (t & 15) * 4;
        float4 f = *(const float4*)&W[(long)(k0 + r) * 3072 + n0 + c4];
        T[(c4 + 0) * 68 + r] = f2bf(f.x);
        T[(c4 + 1) * 68 + r] = f2bf(f.y);
        T[(c4 + 2) * 68 + r] = f2bf(f.z);
        T[(c4 + 3) * 68 + r] = f2bf(f.w);
    }
    __syncthreads();
    #pragma unroll
    for (int i = 0; i < 4; i++) {
        int n  = (t >> 4) + i * 16;
        int k4 = (t & 15) * 4;
        us4 o;
        o.x = T[n * 68 + k4];     o.y = T[n * 68 + k4 + 1];
        o.z = T[n * 68 + k4 + 2]; o.w = T[n * 68 + k4 + 3];
        *(us4*)&Wt[(long)(n0 + n) * 1024 + k0 + k4] = o;
    }
}

// ---------------------------------------------------------------------------
// Kernel 1: qkv = x @ W_qkv via bf16 MFMA; q,k,v row-major [bh][n][d].
// BK=32 linear LDS, global_load_lds width=16, TRIPLE-buffered with counted
// vmcnt (T4): per iteration kt:
//   s_waitcnt vmcnt(4)   -> stage(kt) landed, stage(kt+1)'s 4 loads in flight
//   s_barrier            -> all waves' stage(kt) landed; buf[kt-1] free
//   stage(kt+2) -> buf[(kt+2)%3]   (== buf[kt-1], freed by the barrier)
//   ds_read + 16 MFMA on buf[kt%3]
// Loads now SPAN barriers instead of draining to 0 at each __syncthreads.
// XCD-swizzled 1-D grid (1536 blocks). Epilogue scalar-hoisted (r7).
// ---------------------------------------------------------------------------
__global__ __launch_bounds__(256) void qkv_mfma(
    const u16* __restrict__ xb, const u16* __restrict__ Wt,
    u16* __restrict__ q, u16* __restrict__ k, u16* __restrict__ v) {
    __shared__ u16 As[3][128 * 32];   // 8 KB each buffer
    __shared__ u16 Bs[3][128 * 32];
    const int t = threadIdx.x, w = t >> 6, lane = t & 63;
    const int quad = lane >> 4, l16 = lane & 15;

    // XCD swizzle: XCD k owns wg in [k*192, (k+1)*192) = 8 full m-rows
    const int lin = blockIdx.x;
    const int wg  = (lin & 7) * 192 + (lin >> 3);
    const int j0  = (wg % 24) * 128;
    const int m0  = (wg / 24) * 128;
    const int mw = (w >> 1) * 64, nw = (w & 1) * 64;

    const int srow = t >> 2;
    const int scol = (t & 3) * 8;

    // hoisted staging pointers, advanced by 32 elems (64 B) per staged tile
    const u16* pa0 = xb + (long)(m0 + srow) * 1024 + scol;
    const u16* pa1 = pa0 + (long)64 * 1024;
    const u16* pb0 = Wt + (long)(j0 + srow) * 1024 + scol;
    const u16* pb1 = pb0 + (long)64 * 1024;
    su32* da0 = (su32*)&As[0][srow * 32 + scol];
    su32* da1 = (su32*)&As[0][(srow + 64) * 32 + scol];
    su32* db0 = (su32*)&Bs[0][srow * 32 + scol];
    su32* db1 = (su32*)&Bs[0][(srow + 64) * 32 + scol];
    const int half = 128 * 32 / 2;    // one buffer, in u32 units (8 KB)

    f32x4 acc[4][4] = {};

    // prologue: stage K-tiles 0 and 1 into buffers 0 and 1
    __builtin_amdgcn_global_load_lds((gu32*)pa0, da0, 16, 0, 0);
    __builtin_amdgcn_global_load_lds((gu32*)pa1, da1, 16, 0, 0);
    __builtin_amdgcn_global_load_lds((gu32*)pb0, db0, 16, 0, 0);
    __builtin_amdgcn_global_load_lds((gu32*)pb1, db1, 16, 0, 0);
    pa0 += 32; pa1 += 32; pb0 += 32; pb1 += 32;
    {
        const int o = half;           // buffer 1
        __builtin_amdgcn_global_load_lds((gu32*)pa0, da0 + o, 16, 0, 0);
        __builtin_amdgcn_global_load_lds((gu32*)pa1, da1 + o, 16, 0, 0);
        __builtin_amdgcn_global_load_lds((gu32*)pb0, db0 + o, 16, 0, 0);
        __builtin_amdgcn_global_load_lds((gu32*)pb1, db1 + o, 16, 0, 0);
        pa0 += 32; pa1 += 32; pb0 += 32; pb1 += 32;
    }

    #pragma unroll 1
    for (int kt = 0; kt < 31; ++kt) {
        asm volatile("s_waitcnt vmcnt(4)" ::: "memory");
        __builtin_amdgcn_s_barrier();

        if (kt + 2 < 32) {            // stage K-tile kt+2 into buf (kt+2)%3
            const int o = ((kt + 2) % 3) * half;
            __builtin_amdgcn_global_load_lds((gu32*)pa0, da0 + o, 16, 0, 0);
            __builtin_amdgcn_global_load_lds((gu32*)pa1, da1 + o, 16, 0, 0);
            __builtin_amdgcn_global_load_lds((gu32*)pb0, db0 + o, 16, 0, 0);
            __builtin_amdgcn_global_load_lds((gu32*)pb1, db1 + o, 16, 0, 0);
            pa0 += 32; pa1 += 32; pb0 += 32; pb1 += 32;
        }

        const int cs = (kt % 3) * (128 * 32);
        short8 af[4], bf[4];
        #pragma unroll
        for (int mt = 0; mt < 4; mt++)
            af[mt] = *(const short8*)&As[0][cs + (mw + mt * 16 + l16) * 32 + quad * 8];
        #pragma unroll
        for (int nt = 0; nt < 4; nt++)
            bf[nt] = *(const short8*)&Bs[0][cs + (nw + nt * 16 + l16) * 32 + quad * 8];
        #pragma unroll
        for (int mt = 0; mt < 4; mt++)
            #pragma unroll
            for (int nt = 0; nt < 4; nt++)
                acc[mt][nt] = __builtin_amdgcn_mfma_f32_16x16x32_bf16(
                    af[mt], bf[nt], acc[mt][nt], 0, 0, 0);
    }

    // tail iteration kt = 31: drain the last stage fully
    {
        asm volatile("s_waitcnt vmcnt(0)" ::: "memory");
        __builtin_amdgcn_s_barrier();
        const int cs = (31 % 3) * (128 * 32);
        short8 af[4], bf[4];
        #pragma unroll
        for (int mt = 0; mt < 4; mt++)
            af[mt] = *(const short8*)&As[0][cs + (mw + mt * 16 + l16) * 32 + quad * 8];
        #pragma unroll
        for (int nt = 0; nt < 4; nt++)
            bf[nt] = *(const short8*)&Bs[0][cs + (nw + nt * 16 + l16) * 32 + quad * 8];
        #pragma unroll
        for (int mt = 0; mt < 4; mt++)
            #pragma unroll
            for (int nt = 0; nt < 4; nt++)
                acc[mt][nt] = __builtin_amdgcn_mfma_f32_16x16x32_bf16(
                    af[mt], bf[nt], acc[mt][nt], 0, 0, 0);
    }

    // ---- epilogue: scalar-hoisted addressing ----
    const int cb0 = j0 + nw;
    const int which = cb0 >> 10;
    u16* dstsel = (which == 0) ? q : (which == 1) ? k : v;
    const int bq = (m0 + mw) >> 11;
    const int nb = (m0 + mw) & 2047;
    const int lanoff = quad * 256 + l16;
    #pragma unroll
    for (int nt = 0; nt < 4; nt++) {
        const int cb = cb0 + nt * 16;
        const int hh = (cb & 1023) >> 6;
        const int dc = cb & 63;
        u16* dstp = dstsel + ((long)(bq * H_ + hh) * N_ + nb) * D_ + dc;
        #pragma unroll
        for (int mt = 0; mt < 4; mt++)
            #pragma unroll
            for (int r = 0; r < 4; r++)
                dstp[(mt * 16 + r) * 64 + lanoff] = f2bf(acc[mt][nt][r]);
    }
}

// ---------------------------------------------------------------------------
// Kernel 1b: vb [bh][n][d] -> vT [bh][d][n] (LDS transpose, XOR swizzle)
// ---------------------------------------------------------------------------
__global__ __launch_bounds__(256) void vt_transpose(
    const u16* __restrict__ vb, u16* __restrict__ vT) {
    __shared__ u16 T[64 * 72];
    const int bh = blockIdx.y;
    const int n0 = blockIdx.x * 64;
    const int t  = threadIdx.x;
    const int jj = t >> 3, kg = (t & 7) * 8;
    #pragma unroll
    for (int i = 0; i < 2; i++) {
        int j = jj + i * 32;
        short8 vv = *(const short8*)&vb[(((long)bh * N_ + n0 + j) << 6) + kg];
        u16* vp = (u16*)&vv;
        int jc = j ^ kg;
        #pragma unroll
        for (int c = 0; c < 8; c++) T[(kg + c) * 72 + jc] = vp[c];
    }
    __syncthreads();
    const int d = t >> 2, sg = (t & 3) * 16, xr = d & 56;
    short8 a0 = *(const short8*)&T[d * 72 + (sg ^ xr)];
    short8 a1 = *(const short8*)&T[d * 72 + ((sg + 8) ^ xr)];
    u16* dst = vT + ((long)bh * 64 + d) * 2048 + n0 + sg;
    *(short8*)dst       = a0;
    *(short8*)(dst + 8) = a1;
}

// ---------------------------------------------------------------------------
// Kernel 2: out_M = beta*M, out_Z = beta*Z
// ---------------------------------------------------------------------------
__global__ __launch_bounds__(256) void init_mz(
    const float* __restrict__ M, const float* __restrict__ Z,
    const float* __restrict__ beta_lin,
    float* __restrict__ outM, float* __restrict__ outZ) {
    float beta = 1.f / (1.f + __expf(-beta_lin[0]));
    beta = fminf(fmaxf(beta, 0.9f), 0.999f);
    int i = blockIdx.x * 256 + threadIdx.x;
    if (i < M_ELEMS) outM[i] = beta * M[i];
    if (i < Z_ELEMS) outZ[i] = beta * Z[i];
}

// ---------------------------------------------------------------------------
// Kernel 3: linear-attention branch via MFMA (round-7 version).
// ---------------------------------------------------------------------------
__global__ __launch_bounds__(256) void linear_mfma(
    const u16* __restrict__ qg, const u16* __restrict__ kg_,
    const u16* __restrict__ vTg, const float* __restrict__ Mg,
    const float* __restrict__ Zg, const float* __restrict__ beta_gate,
    float* __restrict__ outA, float* __restrict__ outM, float* __restrict__ outZ) {
    __shared__ u16 MTz[80 * 72];
    __shared__ u16 sqsh[64 * 72];
    __shared__ u16 sksh[64 * 72];
    __shared__ u16 skT[64 * 72];
    __shared__ u16 vT[64 * 72];
    __shared__ u16 vmT[80 * 72];
    __shared__ float dks[64];

    const int bh = blockIdx.y, b = bh >> 4, h = bh & 15;
    const int t = threadIdx.x, w = t >> 6, lane = t & 63;
    const int quad = lane >> 4, l16 = lane & 15;
    const long bhN = (long)bh * N_;

    #pragma unroll
    for (int i = 0; i < 4; i++) {
        int d  = (t >> 4) + i * 16;
        int c4 = (t & 15) * 4;
        float4 f = *(const float4*)&Mg[bh * 4096 + d * 64 + c4];
        MTz[(c4 + 0) * 72 + d] = f2bf(f.x);
        MTz[(c4 + 1) * 72 + d] = f2bf(f.y);
        MTz[(c4 + 2) * 72 + d] = f2bf(f.z);
        MTz[(c4 + 3) * 72 + d] = f2bf(f.w);
    }
    if (t < 64) {
        MTz[64 * 72 + t] = f2bf(Zg[bh * 64 + t]);
        vmT[64 * 72 + t] = f2bf(1.0f);
    }
    for (int e = t; e < 15 * 72; e += 256) {
        MTz[65 * 72 + e] = 0;
        vmT[65 * 72 + e] = 0;
    }
    if (t >= 64 && t < 72) { MTz[64 * 72 + t] = 0; vmT[64 * 72 + t] = 0; }

    const float g = 1.f / (1.f + __expf(-beta_gate[h]));

    f32x4 macc[5] = {};

    const int jj = t >> 3;
    const int kgp = (t & 7) * 8;
    const int srow = t >> 2;
    const int sg   = (t & 3) * 16;

    for (int c0 = 0; c0 < 256; c0 += 64) {
        const int n0c = blockIdx.x * 256 + c0;
        __syncthreads();

        #pragma unroll
        for (int i = 0; i < 2; i++) {
            int j = jj + i * 32;
            long gb = ((bhN + n0c + j) << 6) + kgp;
            short8 q8 = sig8(*(const short8*)&qg[gb]);
            short8 k8 = sig8(*(const short8*)&kg_[gb]);
            *(short8*)&sqsh[j * 72 + kgp] = q8;
            *(short8*)&sksh[j * 72 + kgp] = k8;
            u16* kp = (u16*)&k8;
            int jc = j ^ kgp;
            #pragma unroll
            for (int c = 0; c < 8; c++) skT[(kgp + c) * 72 + jc] = kp[c];
        }
        {
            const u16* vp = vTg + ((long)bh * 64 + srow) * 2048 + n0c + sg;
            *(short8*)&vT[srow * 72 + sg]     = *(const short8*)vp;
            *(short8*)&vT[srow * 72 + sg + 8] = *(const short8*)(vp + 8);
        }
        __syncthreads();

        // --- MFMA1: A_raw = sq @ MTz ---
        {
            short8 a0 = *(const short8*)&sqsh[(w * 16 + l16) * 72 + quad * 8];
            short8 a1 = *(const short8*)&sqsh[(w * 16 + l16) * 72 + 32 + quad * 8];
            f32x4 am[5];
            #pragma unroll
            for (int ct = 0; ct < 5; ct++) {
                short8 b0 = *(const short8*)&MTz[(ct * 16 + l16) * 72 + quad * 8];
                short8 b1 = *(const short8*)&MTz[(ct * 16 + l16) * 72 + 32 + quad * 8];
                f32x4 acc = {};
                acc = __builtin_amdgcn_mfma_f32_16x16x32_bf16(a0, b0, acc, 0, 0, 0);
                acc = __builtin_amdgcn_mfma_f32_16x16x32_bf16(a1, b1, acc, 0, 0, 0);
                am[ct] = acc;
            }
            #pragma unroll
            for (int r = 0; r < 4; r++) {
                float dq  = __shfl(am[4][r], lane & 48, 64);
                float inv = __builtin_amdgcn_rcpf(dq);
                int n = n0c + w * 16 + quad * 4 + r;
                long row = ((long)(b * N_ + n)) * INNER_ + h * 64;
                #pragma unroll
                for (int ct = 0; ct < 4; ct++)
                    outA[row + ct * 16 + l16] = g * am[ct][r] * inv;
            }
        }

        // --- MFMA2: momentT = MTz @ sk ---
        f32x4 mt_[4];
        {
            short8 a0 = *(const short8*)&MTz[(w * 16 + l16) * 72 + quad * 8];
            short8 a1 = *(const short8*)&MTz[(w * 16 + l16) * 72 + 32 + quad * 8];
            #pragma unroll
            for (int ct = 0; ct < 4; ct++) {
                short8 b0 = *(const short8*)&sksh[(ct * 16 + l16) * 72 + quad * 8];
                short8 b1 = *(const short8*)&sksh[(ct * 16 + l16) * 72 + 32 + quad * 8];
                f32x4 acc = {};
                acc = __builtin_amdgcn_mfma_f32_16x16x32_bf16(a0, b0, acc, 0, 0, 0);
                acc = __builtin_amdgcn_mfma_f32_16x16x32_bf16(a1, b1, acc, 0, 0, 0);
                mt_[ct] = acc;
            }
            short8 z0 = *(const short8*)&MTz[(64 + l16) * 72 + quad * 8];
            short8 z1 = *(const short8*)&MTz[(64 + l16) * 72 + 32 + quad * 8];
            short8 b0 = *(const short8*)&sksh[(w * 16 + l16) * 72 + quad * 8];
            short8 b1 = *(const short8*)&sksh[(w * 16 + l16) * 72 + 32 + quad * 8];
            f32x4 acc = {};
            acc = __builtin_amdgcn_mfma_f32_16x16x32_bf16(z0, b0, acc, 0, 0, 0);
            acc = __builtin_amdgcn_mfma_f32_16x16x32_bf16(z1, b1, acc, 0, 0, 0);
            if (quad == 0) dks[w * 16 + l16] = __builtin_amdgcn_rcpf(acc[0]);
        }
        __syncthreads();

        // --- vmT = vT - momentT/dk (bf16) ---
        #pragma unroll
        for (int ct = 0; ct < 4; ct++) {
            float invdk = dks[ct * 16 + l16];
            #pragma unroll
            for (int r = 0; r < 4; r++) {
                int vd = w * 16 + quad * 4 + r;
                float vv = bf2f(vT[vd * 72 + ct * 16 + l16]);
                vmT[vd * 72 + ct * 16 + l16] = f2bf(vv - mt_[ct][r] * invdk);
            }
        }
        __syncthreads();

        // --- MFMA3: Macc += skT @ [vm | 1] ---
        {
            int drow = w * 16 + l16, xr = drow & 56;
            short8 a0 = *(const short8*)&skT[drow * 72 + ((quad * 8) ^ xr)];
            short8 a1 = *(const short8*)&skT[drow * 72 + ((32 + quad * 8) ^ xr)];
            #pragma unroll
            for (int ct = 0; ct < 5; ct++) {
                short8 b0 = *(const short8*)&vmT[(ct * 16 + l16) * 72 + quad * 8];
                short8 b1 = *(const short8*)&vmT[(ct * 16 + l16) * 72 + 32 + quad * 8];
                macc[ct] = __builtin_amdgcn_mfma_f32_16x16x32_bf16(a0, b0, macc[ct], 0, 0, 0);
                macc[ct] = __builtin_amdgcn_mfma_f32_16x16x32_bf16(a1, b1, macc[ct], 0, 0, 0);
            }
        }
    }

    #pragma unroll
    for (int ct = 0; ct < 4; ct++)
        #pragma unroll
        for (int r = 0; r < 4; r++) {
            int d = w * 16 + quad * 4 + r;
            atomicAdd(&outM[bh * 4096 + d * 64 + ct * 16 + l16], macc[ct][r]);
        }
    if (l16 == 0)
        #pragma unroll
        for (int r = 0; r < 4; r++)
            atomicAdd(&outZ[bh * 64 + w * 16 + quad * 4 + r], macc[4][r]);
}

// ---------------------------------------------------------------------------
// Kernel 4: flash attention — round-6 version (unchanged): 256 thr, 256-row
// Q-tile, grid 512, __launch_bounds__(256,2) VGPR unlock, pad-68 LDS,
// setprio around MFMA clusters, XCD swizzle.
// ---------------------------------------------------------------------------
__global__ __launch_bounds__(256, 2) void flash_mfma(
    const u16* __restrict__ qb, const u16* __restrict__ kb,
    const u16* __restrict__ vTg, const float* __restrict__ beta_gate,
    float* __restrict__ outA) {
    __shared__ u16 Ks[64 * 68];        // permuted-row K tile [row][d], pad 68
    __shared__ u16 Vt[64 * 68];        // [d][key] straight, pad 68

    // XCD swizzle: nwg = 512, XCD k gets wg in [k*64,(k+1)*64) = 8 bh
    const int lin = blockIdx.x;
    const int wg  = (lin & 7) * 64 + (lin >> 3);
    const int bh  = wg >> 3;
    const int n0  = (wg & 7) * 256;
    const int b = bh >> 4, h = bh & 15;
    const int t = threadIdx.x, w = t >> 6, lane = t & 63;
    const int quad = lane >> 4, l16 = lane & 15;
    const long bhN = (long)bh * N_;

    const int srow = t >> 2;           // 0..63 : key offset within tile
    const int sg   = (t & 3) * 16;
    // permuted LDS row for K: sigma(j) = ((j&4)<<2) + ((j>>3)<<2) + (j&3), per 32-block
    const int jloc = srow & 31;
    const int krow = (srow & 32) + ((jloc & 4) << 2) + ((jloc >> 3) << 2) + (jloc & 3);

    const u16* kbase  = kb + (bhN << 6);
    const u16* vtbase = vTg + (long)bh * 64 * 2048;

    short8 qf[4][2];
    #pragma unroll
    for (int mi = 0; mi < 4; mi++) {
        long qrow = bhN + n0 + w * 64 + mi * 16 + l16;
        qf[mi][0] = *(const short8*)&qb[(qrow << 6) + quad * 8];
        qf[mi][1] = *(const short8*)&qb[(qrow << 6) + 32 + quad * 8];
        // fold the softmax scale into q once (register-resident)
        #pragma unroll
        for (int z = 0; z < 2; z++) {
            u16* p = (u16*)&qf[mi][z];
            #pragma unroll
            for (int c = 0; c < 8; c++) p[c] = f2bf(bf2f(p[c]) * SC_LOG2E);
        }
    }

    const short8 onesf = {0x3F80, 0x3F80, 0x3F80, 0x3F80,
                          0x3F80, 0x3F80, 0x3F80, 0x3F80};  // bf16 1.0 x8

    // prefetch tile 0
    short8 kr0, kr1, vr0, vr1;
    {
        const u16* kp = kbase + ((long)srow << 6) + sg;
        kr0 = *(const short8*)kp;
        kr1 = *(const short8*)(kp + 8);
        const u16* vp = vtbase + (long)srow * 2048 + sg;
        vr0 = *(const short8*)vp;
        vr1 = *(const short8*)(vp + 8);
    }

    f32x4 of[4][4] = {};
    f32x4 ol[4] = {};

    for (int j0 = 0; j0 < N_; j0 += 64) {
        __syncthreads();
        *(short8*)&Ks[krow * 68 + sg]     = kr0;
        *(short8*)&Ks[krow * 68 + sg + 8] = kr1;
        *(short8*)&Vt[srow * 68 + sg]     = vr0;
        *(short8*)&Vt[srow * 68 + sg + 8] = vr1;
        __syncthreads();

        if (j0 + 64 < N_) {   // prefetch next tile during compute
            const u16* kp = kbase + ((long)(j0 + 64 + srow) << 6) + sg;
            kr0 = *(const short8*)kp;
            kr1 = *(const short8*)(kp + 8);
            const u16* vp = vtbase + (long)srow * 2048 + j0 + 64 + sg;
            vr0 = *(const short8*)vp;
            vr1 = *(const short8*)(vp + 8);
        }

        #pragma unroll
        for (int g = 0; g < 2; g++) {
            const int rb = g * 32;
            // A-frag rows l16 -> keys rb+kperm(l16) (st0); rows 16+l16 -> +4 (st1)
            short8 kA0 = *(const short8*)&Ks[(rb + l16) * 68 + quad * 8];
            short8 kA1 = *(const short8*)&Ks[(rb + l16) * 68 + 32 + quad * 8];
            short8 kB0 = *(const short8*)&Ks[(rb + 16 + l16) * 68 + quad * 8];
            short8 kB1 = *(const short8*)&Ks[(rb + 16 + l16) * 68 + 32 + quad * 8];
            // V B-frags: B[k=key quad*8+j][n=d l16], contiguous keys
            short8 vf[4];
            #pragma unroll
            for (int nt = 0; nt < 4; nt++)
                vf[nt] = *(const short8*)&Vt[(nt * 16 + l16) * 68 + rb + quad * 8];

            #pragma unroll
            for (int mi = 0; mi < 4; mi++) {
                f32x4 st0 = {}, st1 = {};
                __builtin_amdgcn_s_setprio(1);
                st0 = __builtin_amdgcn_mfma_f32_16x16x32_bf16(kA0, qf[mi][0], st0, 0, 0, 0);
                st0 = __builtin_amdgcn_mfma_f32_16x16x32_bf16(kA1, qf[mi][1], st0, 0, 0, 0);
                st1 = __builtin_amdgcn_mfma_f32_16x16x32_bf16(kB0, qf[mi][0], st1, 0, 0, 0);
                st1 = __builtin_amdgcn_mfma_f32_16x16x32_bf16(kB1, qf[mi][1], st1, 0, 0, 0);
                __builtin_amdgcn_s_setprio(0);
                // lane holds S[key rb+quad*8+r][Q-row l16] (st0 r=0..3, st1 +4)
                float p0 = __builtin_amdgcn_exp2f(st0[0]);
                float p1 = __builtin_amdgcn_exp2f(st0[1]);
                float p2 = __builtin_amdgcn_exp2f(st0[2]);
                float p3 = __builtin_amdgcn_exp2f(st0[3]);
                float p4 = __builtin_amdgcn_exp2f(st1[0]);
                float p5 = __builtin_amdgcn_exp2f(st1[1]);
                float p6 = __builtin_amdgcn_exp2f(st1[2]);
                float p7 = __builtin_amdgcn_exp2f(st1[3]);
                // pack to PV A-frag: A[m=l16][k=quad*8+j] == P — layout identity
                short8 af;
                unsigned int* au = (unsigned int*)&af;
                au[0] = __builtin_amdgcn_perm(__float_as_uint(p1), __float_as_uint(p0),
                                              0x07060302u);
                au[1] = __builtin_amdgcn_perm(__float_as_uint(p3), __float_as_uint(p2),
                                              0x07060302u);
                au[2] = __builtin_amdgcn_perm(__float_as_uint(p5), __float_as_uint(p4),
                                              0x07060302u);
                au[3] = __builtin_amdgcn_perm(__float_as_uint(p7), __float_as_uint(p6),
                                              0x07060302u);
                __builtin_amdgcn_s_setprio(1);
                ol[mi] = __builtin_amdgcn_mfma_f32_16x16x32_bf16(af, onesf, ol[mi], 0, 0, 0);
                #pragma unroll
                for (int nt = 0; nt < 4; nt++)
                    of[mi][nt] = __builtin_amdgcn_mfma_f32_16x16x32_bf16(
                        af, vf[nt], of[mi][nt], 0, 0, 0);
                __builtin_amdgcn_s_setprio(0);
            }
        }
    }

    const float g  = 1.f / (1.f + __expf(-beta_gate[h]));
    const float gi = 1.f - g;
    #pragma unroll
    for (int mi = 0; mi < 4; mi++) {
        #pragma unroll
        for (int r = 0; r < 4; r++) {
            // ol[mi][r] = l for Q-row mi*16+quad*4+r (C/D row = quad*4+r)
            float sc = gi / ol[mi][r];
            int n = n0 + w * 64 + mi * 16 + quad * 4 + r;
            #pragma unroll
            for (int nt = 0; nt < 4; nt++) {
                long idx = ((long)(b * N_ + n)) * INNER_ + h * 64 + nt * 16 + l16;
                outA[idx] += sc * of[mi][nt][r];
            }
        }
    }
}

extern "C" void kernel_launch(void* const* d_in, const int* in_sizes, int n_in,
                              void* d_out, int out_size, void* d_ws, size_t ws_size,
                              hipStream_t stream) {
    const float* x         = (const float*)d_in[0];
    const float* M         = (const float*)d_in[1];
    const float* Z         = (const float*)d_in[2];
    const float* W         = (const float*)d_in[3];
    const float* beta_lin  = (const float*)d_in[4];
    const float* beta_gate = (const float*)d_in[5];

    float* out  = (float*)d_out;
    float* outA = out;
    float* outM = out + A_ELEMS;
    float* outZ = out + A_ELEMS + M_ELEMS;

    u16* xb = (u16*)d_ws;                         // [8192][1024]
    u16* Wt = xb + (size_t)8192 * 1024;           // [3072][1024]
    u16* qb = Wt + (size_t)3072 * 1024;           // [bh][n][d]
    u16* kb = qb + (size_t)BH_ * N_ * D_;         // [bh][n][d]
    u16* vb = kb + (size_t)BH_ * N_ * D_;         // [bh][n][d]
    u16* vt = vb + (size_t)BH_ * N_ * D_;         // [bh][d][n]

    cvt_x<<<dim3(A_ELEMS / 1024), 256, 0, stream>>>(x, xb);
    cvt_w<<<dim3(48, 16), 256, 0, stream>>>(W, Wt);
    qkv_mfma<<<dim3(1536), 256, 0, stream>>>(xb, Wt, qb, kb, vb);
    vt_transpose<<<dim3(N_ / 64, BH_), 256, 0, stream>>>(vb, vt);
    init_mz<<<dim3((M_ELEMS + 255) / 256), 256, 0, stream>>>(M, Z, beta_lin, outM, outZ);
    linear_mfma<<<dim3(8, BH_), 256, 0, stream>>>(qb, kb, vt, M, Z, beta_gate,
                                                  outA, outM, outZ);
    flash_mfma<<<dim3(N_ / 256 * BH_), 256, 0, stream>>>(qb, kb, vt, beta_gate, outA);
}